// Round 12
// baseline (178.611 us; speedup 1.0000x reference)
//
#include <hip/hip_runtime.h>
#include <math.h>

// ---------------------------------------------------------------------------
// GAT layer. Split-bf16 MFMA MLP (A/W hi-lo split, single-bf16 full-width h1
// in LDS, 8 waves/block) + bucketed online-softmax aggregation (16-lane edge
// groups, 2 edges per group per iter) with eh-copy folded into the launch.
//   n_h = relu(nh@W1+b1)@W2+b2
//   attn[e] = dot(n_h[src], n_h[dst]);  segment-softmax over dst
//   out0 = n_h + segsum(softmax * n_h[src]);  out1 = eh
// ---------------------------------------------------------------------------

#define D_IN   128
#define D_HID  256
#define D_OUT  128

typedef short bf16x8 __attribute__((ext_vector_type(8)));
typedef float f32x4  __attribute__((ext_vector_type(4)));

__device__ __forceinline__ short f2bf(float f)
{
    unsigned int u = __float_as_uint(f);
    unsigned int r = (u + 0x7fffu + ((u >> 16) & 1u)) >> 16;   // RNE
    return (short)r;
}
__device__ __forceinline__ float bf2f(short h)
{
    return __uint_as_float(((unsigned int)(unsigned short)h) << 16);
}

// ---------------------------------------------------------------------------
// pack W[K][N] fp32 into MFMA B-fragment hi/lo bf16 planes
// ---------------------------------------------------------------------------
__device__ __forceinline__ void pack_body(const float* __restrict__ W,
                                          short* __restrict__ Bh,
                                          short* __restrict__ Bl,
                                          int K, int N, int u)
{
    const int T = K >> 5;
    const int l = u & 63;
    const int t = (u >> 6) % T;
    const int c = u / (64 * T);
    const int lr = l & 15, kb = l >> 4;
    bf16x8 vh, vl;
#pragma unroll
    for (int j = 0; j < 8; ++j) {
        int k   = t * 32 + kb * 8 + j;
        int col = c * 16 + lr;
        float x = W[(size_t)k * N + col];
        short hi = f2bf(x);
        vh[j] = hi;
        vl[j] = f2bf(x - bf2f(hi));
    }
    *(bf16x8*)(Bh + (size_t)u * 8) = vh;
    *(bf16x8*)(Bl + (size_t)u * 8) = vl;
}

// ---------------------------------------------------------------------------
// prep: A hi/lo split + both weight packs + zero count (tail blocks)
// grid = nAB + 32 + NB
// ---------------------------------------------------------------------------
__global__ __launch_bounds__(256)
void prep(const float* __restrict__ A, short* __restrict__ Ah,
          short* __restrict__ Al, long valid, long total8, int nAB,
          const float* __restrict__ W1, short* __restrict__ B1h,
          short* __restrict__ B1l,
          const float* __restrict__ W2, short* __restrict__ B2h,
          short* __restrict__ B2l,
          unsigned int* __restrict__ count, int N)
{
    int b = blockIdx.x;
    const int tid = threadIdx.x;
    if (b < nAB) {                                    // A split
        long t = (long)b * 256 + tid;
        if (t < total8) {
            long base = t * 8;
            bf16x8 vh, vl;
            if (base < valid) {
                float4 f0 = *(const float4*)(A + base);
                float4 f1 = *(const float4*)(A + base + 4);
                float fv[8] = {f0.x, f0.y, f0.z, f0.w, f1.x, f1.y, f1.z, f1.w};
#pragma unroll
                for (int j = 0; j < 8; ++j) {
                    short hi = f2bf(fv[j]);
                    vh[j] = hi;
                    vl[j] = f2bf(fv[j] - bf2f(hi));
                }
            } else {
                vh = (bf16x8)0; vl = (bf16x8)0;
            }
            *(bf16x8*)(Ah + base) = vh;
            *(bf16x8*)(Al + base) = vl;
        }
        return;
    }
    b -= nAB;
    if (b < 32) {                                     // weight packs (16+16)
        if (b < 16) pack_body(W1, B1h, B1l, D_IN, D_HID, b * 256 + tid);
        else        pack_body(W2, B2h, B2l, D_HID, D_OUT, (b - 16) * 256 + tid);
        return;
    }
    b -= 32;                                          // zero count
    int i = b * 256 + tid;
    if (i < N) count[i] = 0u;
}

// ---------------------------------------------------------------------------
// dst histogram (standalone — atomics must not share a kernel with streaming)
// ---------------------------------------------------------------------------
__global__ __launch_bounds__(256)
void hist_pos(const int* __restrict__ dst, unsigned int* __restrict__ count,
              unsigned int* __restrict__ pos, int E)
{
    int e = blockIdx.x * blockDim.x + threadIdx.x;
    if (e < E) pos[e] = atomicAdd(count + dst[e], 1u);
}

// ---------------------------------------------------------------------------
// scan_all: single-launch exclusive scan. Block b redundantly sums all
// counts before its chunk (coalesced, L2-hit), then local-scans its 256.
// ---------------------------------------------------------------------------
__global__ __launch_bounds__(256)
void scan_all(const unsigned int* __restrict__ count,
              unsigned int* __restrict__ off, int n)
{
    __shared__ unsigned int lds[256];
    const int t = threadIdx.x;
    const int b = blockIdx.x;

    // 1) base = sum(count[0 .. b*256))
    unsigned int s = 0;
    for (int i = t; i < b * 256; i += 256) s += count[i];
    lds[t] = s;
    __syncthreads();
#pragma unroll
    for (int d = 128; d > 0; d >>= 1) {
        if (t < d) lds[t] += lds[t + d];
        __syncthreads();
    }
    unsigned int base = lds[0];
    __syncthreads();

    // 2) local inclusive scan of this chunk
    int i = b * 256 + t;
    unsigned int v = (i < n) ? count[i] : 0u;
    lds[t] = v;
    __syncthreads();
#pragma unroll
    for (int d = 1; d < 256; d <<= 1) {
        unsigned int x = lds[t];
        unsigned int add = (t >= d) ? lds[t - d] : 0u;
        __syncthreads();
        lds[t] = x + add;
        __syncthreads();
    }
    unsigned int incl = lds[t];
    if (i < n)      off[i] = base + incl - v;
    if (i == n - 1) off[n] = base + incl;
}

__global__ __launch_bounds__(256)
void fill_srcs(const int* __restrict__ src, const int* __restrict__ dst,
               const unsigned int* __restrict__ off,
               const unsigned int* __restrict__ pos,
               int* __restrict__ srcs, int E)
{
    int e = blockIdx.x * blockDim.x + threadIdx.x;
    if (e >= E) return;
    srcs[off[dst[e]] + pos[e]] = src[e];
}

// ---------------------------------------------------------------------------
// Fused MLP, BM=64, 8 waves (512 thr). Wave (wr = w>>2, wc = w&3):
//   GEMM1: rows [wr*32,+32) x h1-cols [wc*64,+64)   acc1[2][4]
//   GEMM2: rows [wr*32,+32) x out-cols [wc*32,+32)  acc2[2][2]
// Full-width single-bf16 h1 in LDS, ONE barrier. Math order per output
// fragment identical to the 4-wave version (bitwise-same results).
// ---------------------------------------------------------------------------
#define H2_STRIDE 264   // 256 + 8 bf16 pad

__global__ __launch_bounds__(512)
void mlp_fused(const short* __restrict__ Ah, const short* __restrict__ Al,
               const short* __restrict__ B1h, const short* __restrict__ B1l,
               const float* __restrict__ b1,
               const short* __restrict__ B2h, const short* __restrict__ B2l,
               const float* __restrict__ b2,
               float* __restrict__ out, short* __restrict__ nhb, int Nvalid)
{
    __shared__ __attribute__((aligned(16))) short H[64 * H2_STRIDE];

    const int w  = threadIdx.x >> 6;      // 0..7
    const int l  = threadIdx.x & 63;
    const int lr = l & 15, kb = l >> 4;
    const int wr = w >> 2;                // 0..1
    const int wc = w & 3;                 // 0..3
    const size_t row0 = (size_t)blockIdx.x * 64;

    // ---- GEMM1
    f32x4 acc1[2][4] = {};
#pragma unroll
    for (int t = 0; t < 4; ++t) {
        bf16x8 ah[2], al[2], bh[4], bl[4];
#pragma unroll
        for (int m = 0; m < 2; ++m) {
            size_t aoff = (row0 + wr * 32 + m * 16 + lr) * D_IN + t * 32 + kb * 8;
            ah[m] = *(const bf16x8*)(Ah + aoff);
            al[m] = *(const bf16x8*)(Al + aoff);
        }
#pragma unroll
        for (int n = 0; n < 4; ++n) {
            int c = wc * 4 + n;                      // h1 col-frag 0..15
            size_t boff = (size_t)((c * 4 + t) * 64 + l) * 8;
            bh[n] = *(const bf16x8*)(B1h + boff);
            bl[n] = *(const bf16x8*)(B1l + boff);
        }
#pragma unroll
        for (int m = 0; m < 2; ++m)
#pragma unroll
            for (int n = 0; n < 4; ++n) {
                acc1[m][n] = __builtin_amdgcn_mfma_f32_16x16x32_bf16(ah[m], bh[n], acc1[m][n], 0, 0, 0);
                acc1[m][n] = __builtin_amdgcn_mfma_f32_16x16x32_bf16(al[m], bh[n], acc1[m][n], 0, 0, 0);
                acc1[m][n] = __builtin_amdgcn_mfma_f32_16x16x32_bf16(ah[m], bl[n], acc1[m][n], 0, 0, 0);
            }
    }

    // ---- bias + relu -> single bf16 -> LDS
#pragma unroll
    for (int n = 0; n < 4; ++n) {
        int col = wc * 64 + n * 16 + lr;
        float bb = b1[col];
#pragma unroll
        for (int m = 0; m < 2; ++m)
#pragma unroll
            for (int i = 0; i < 4; ++i) {
                int lrow = wr * 32 + m * 16 + kb * 4 + i;
                float v = fmaxf(acc1[m][n][i] + bb, 0.f);
                H[lrow * H2_STRIDE + col] = f2bf(v);
            }
    }
    __syncthreads();

    // ---- GEMM2
    f32x4 acc2[2][2] = {};
#pragma unroll
    for (int t2 = 0; t2 < 8; ++t2) {
        bf16x8 a[2], bh[2], bl[2];
#pragma unroll
        for (int m = 0; m < 2; ++m)
            a[m] = *(const bf16x8*)&H[(wr * 32 + m * 16 + lr) * H2_STRIDE + t2 * 32 + kb * 8];
#pragma unroll
        for (int n = 0; n < 2; ++n) {
            int c = wc * 2 + n;                      // out col-frag 0..7
            size_t boff = (size_t)((c * 8 + t2) * 64 + l) * 8;
            bh[n] = *(const bf16x8*)(B2h + boff);
            bl[n] = *(const bf16x8*)(B2l + boff);
        }
#pragma unroll
        for (int m = 0; m < 2; ++m)
#pragma unroll
            for (int n = 0; n < 2; ++n) {
                acc2[m][n] = __builtin_amdgcn_mfma_f32_16x16x32_bf16(a[m], bh[n], acc2[m][n], 0, 0, 0);
                acc2[m][n] = __builtin_amdgcn_mfma_f32_16x16x32_bf16(a[m], bl[n], acc2[m][n], 0, 0, 0);
            }
    }

    // ---- epilogue
#pragma unroll
    for (int n = 0; n < 2; ++n) {
        int col = wc * 32 + n * 16 + lr;
        float bb = b2[col];
#pragma unroll
        for (int m = 0; m < 2; ++m)
#pragma unroll
            for (int i = 0; i < 4; ++i) {
                size_t row = row0 + wr * 32 + m * 16 + kb * 4 + i;
                float v = acc2[m][n][i] + bb;
                nhb[row * D_OUT + col] = f2bf(v);
                if ((int)row < Nvalid) out[row * D_OUT + col] = v;
            }
    }
}

// ---------------------------------------------------------------------------
// agg_copy: blocks [0, copyB) stream the eh passthrough; blocks [copyB, ...)
// run node aggregation: one wave per dst node, 4 groups x 16 lanes,
// 2 edges per group per iteration (8 edges/wave-iter), online softmax.
// ---------------------------------------------------------------------------
#define NEG_HUGE -3.0e38f

__global__ __launch_bounds__(256)
void agg_copy(const short* __restrict__ nhb,
              const unsigned int* __restrict__ off,
              const int* __restrict__ srcs,
              float* __restrict__ out, int N,
              const float4* __restrict__ ehin, float4* __restrict__ ehout,
              int n4, int copyB)
{
    if ((int)blockIdx.x < copyB) {                    // eh copy
        for (int i = blockIdx.x * 256 + threadIdx.x; i < n4; i += copyB * 256)
            ehout[i] = ehin[i];
        return;
    }
    int wid  = (((int)blockIdx.x - copyB) * 256 + (int)threadIdx.x) >> 6;
    int lane = threadIdx.x & 63;
    if (wid >= N) return;
    const int g = lane >> 4;      // edge-group 0..3
    const int j = lane & 15;      // dim-lane

    const float* sp = out + (size_t)wid * D_OUT + j * 8;
    const float4 sa = *(const float4*)sp;
    const float4 sb = *(const float4*)(sp + 4);

    const unsigned int beg = off[wid];
    const unsigned int end = off[wid + 1];

    float m = NEG_HUGE, den = 0.f;
    float c0 = 0.f, c1 = 0.f, c2 = 0.f, c3 = 0.f;
    float c4 = 0.f, c5 = 0.f, c6 = 0.f, c7 = 0.f;

    for (unsigned int base = beg; base < end; base += 8) {
        unsigned int idx0 = base + g * 2;
        unsigned int idx1 = idx0 + 1;
        bool v0 = idx0 < end, v1 = idx1 < end;
        int s0 = v0 ? srcs[idx0] : 0;
        int s1 = v1 ? srcs[idx1] : 0;
        uint4 A0 = *(const uint4*)(nhb + (size_t)s0 * D_OUT + j * 8);
        uint4 A1 = *(const uint4*)(nhb + (size_t)s1 * D_OUT + j * 8);

        float a00 = __uint_as_float(A0.x << 16), a01 = __uint_as_float(A0.x & 0xffff0000u);
        float a02 = __uint_as_float(A0.y << 16), a03 = __uint_as_float(A0.y & 0xffff0000u);
        float a04 = __uint_as_float(A0.z << 16), a05 = __uint_as_float(A0.z & 0xffff0000u);
        float a06 = __uint_as_float(A0.w << 16), a07 = __uint_as_float(A0.w & 0xffff0000u);
        float a10 = __uint_as_float(A1.x << 16), a11 = __uint_as_float(A1.x & 0xffff0000u);
        float a12 = __uint_as_float(A1.y << 16), a13 = __uint_as_float(A1.y & 0xffff0000u);
        float a14 = __uint_as_float(A1.z << 16), a15 = __uint_as_float(A1.z & 0xffff0000u);
        float a16 = __uint_as_float(A1.w << 16), a17 = __uint_as_float(A1.w & 0xffff0000u);

        float p0 = a00 * sa.x + a01 * sa.y + a02 * sa.z + a03 * sa.w
                 + a04 * sb.x + a05 * sb.y + a06 * sb.z + a07 * sb.w;
        float p1 = a10 * sa.x + a11 * sa.y + a12 * sa.z + a13 * sa.w
                 + a14 * sb.x + a15 * sb.y + a16 * sb.z + a17 * sb.w;
        p0 += __shfl_xor(p0, 1);  p1 += __shfl_xor(p1, 1);
        p0 += __shfl_xor(p0, 2);  p1 += __shfl_xor(p1, 2);
        p0 += __shfl_xor(p0, 4);  p1 += __shfl_xor(p1, 4);
        p0 += __shfl_xor(p0, 8);  p1 += __shfl_xor(p1, 8);

        float p0v = v0 ? p0 : NEG_HUGE;
        float p1v = v1 ? p1 : NEG_HUGE;
        float mnew = fmaxf(m, fmaxf(p0v, p1v));
        float scale = __expf(m - mnew);
        float w0 = v0 ? __expf(p0 - mnew) : 0.f;
        float w1 = v1 ? __expf(p1 - mnew) : 0.f;
        den = fmaf(den, scale, w0 + w1);
        c0 = fmaf(c0, scale, fmaf(w0, a00, w1 * a10));
        c1 = fmaf(c1, scale, fmaf(w0, a01, w1 * a11));
        c2 = fmaf(c2, scale, fmaf(w0, a02, w1 * a12));
        c3 = fmaf(c3, scale, fmaf(w0, a03, w1 * a13));
        c4 = fmaf(c4, scale, fmaf(w0, a04, w1 * a14));
        c5 = fmaf(c5, scale, fmaf(w0, a05, w1 * a15));
        c6 = fmaf(c6, scale, fmaf(w0, a06, w1 * a16));
        c7 = fmaf(c7, scale, fmaf(w0, a07, w1 * a17));
        m = mnew;
    }

    // merge the 4 group states (flash-style)
#pragma unroll
    for (int o = 16; o < 64; o <<= 1) {
        float m2 = __shfl_xor(m, o);
        float d2 = __shfl_xor(den, o);
        float b0 = __shfl_xor(c0, o), b1 = __shfl_xor(c1, o);
        float b2v = __shfl_xor(c2, o), b3 = __shfl_xor(c3, o);
        float b4 = __shfl_xor(c4, o), b5 = __shfl_xor(c5, o);
        float b6 = __shfl_xor(c6, o), b7 = __shfl_xor(c7, o);
        float mn = fmaxf(m, m2);
        float s1 = __expf(m - mn);
        float s2 = __expf(m2 - mn);
        den = den * s1 + d2 * s2;
        c0 = c0 * s1 + b0 * s2;  c1 = c1 * s1 + b1 * s2;
        c2 = c2 * s1 + b2v * s2; c3 = c3 * s1 + b3 * s2;
        c4 = c4 * s1 + b4 * s2;  c5 = c5 * s1 + b5 * s2;
        c6 = c6 * s1 + b6 * s2;  c7 = c7 * s1 + b7 * s2;
        m = mn;
    }

    float inv = (den > 0.f) ? 1.f / den : 0.f;
    if (g == 0) {
        float4 o0, o1;
        o0.x = sa.x + c0 * inv; o0.y = sa.y + c1 * inv;
        o0.z = sa.z + c2 * inv; o0.w = sa.w + c3 * inv;
        o1.x = sb.x + c4 * inv; o1.y = sb.y + c5 * inv;
        o1.z = sb.z + c6 * inv; o1.w = sb.w + c7 * inv;
        float* op = out + (size_t)wid * D_OUT + j * 8;
        *(float4*)op = o0;
        *(float4*)(op + 4) = o1;
    }
}

// ---------------------------------------------------------------------------
extern "C" void kernel_launch(void* const* d_in, const int* in_sizes, int n_in,
                              void* d_out, int out_size, void* d_ws, size_t ws_size,
                              hipStream_t stream)
{
    const float* nh  = (const float*)d_in[0];
    const float* eh  = (const float*)d_in[1];
    const int*   ei  = (const int*)d_in[2];
    const float* W1  = (const float*)d_in[3];
    const float* b1  = (const float*)d_in[4];
    const float* W2  = (const float*)d_in[5];
    const float* b2  = (const float*)d_in[6];

    const int N  = in_sizes[0] / D_IN;        // 50000
    const int E  = in_sizes[2] / 2;           // 800000
    const int EH = in_sizes[1];               // E*16 floats
    const int Mp = (N + 63) & ~63;            // padded rows (50048)
    const int NB = (N + 255) / 256;           // scan chunks (196)

    const int* src = ei;
    const int* dst = ei + E;

    float* out_nh = (float*)d_out;
    float* out_eh = (float*)d_out + (size_t)N * D_OUT;

    // workspace (~46 MB)
    char* ws = (char*)d_ws;
    size_t o = 0;
    short* Ahp = (short*)(ws + o); o += (size_t)Mp * D_IN * 2;
    short* Alp = (short*)(ws + o); o += (size_t)Mp * D_IN * 2;
    short* nhb = (short*)(ws + o); o += (size_t)Mp * D_OUT * 2;
    short* B1h = (short*)(ws + o); o += (size_t)D_IN  * D_HID * 2;
    short* B1l = (short*)(ws + o); o += (size_t)D_IN  * D_HID * 2;
    short* B2h = (short*)(ws + o); o += (size_t)D_HID * D_OUT * 2;
    short* B2l = (short*)(ws + o); o += (size_t)D_HID * D_OUT * 2;
    int*          srcs  = (int*)(ws + o);          o += (size_t)E * 4;
    unsigned int* pos   = (unsigned int*)(ws + o); o += (size_t)E * 4;
    unsigned int* count = (unsigned int*)(ws + o); o += (size_t)N * 4;
    unsigned int* off   = (unsigned int*)(ws + o); o += (size_t)(N + 1) * 4;

    // 1) prep: A split + packs + zero count
    {
        long total8 = (long)Mp * D_IN / 8;
        int  nAB    = (int)((total8 + 255) / 256);
        prep<<<nAB + 32 + NB, 256, 0, stream>>>(
            nh, Ahp, Alp, (long)N * D_IN, total8, nAB,
            W1, B1h, B1l, W2, B2h, B2l, count, N);
    }

    // 2) histogram + single-launch scan + fill
    hist_pos<<<(E + 255) / 256, 256, 0, stream>>>(dst, count, pos, E);
    scan_all<<<NB, 256, 0, stream>>>(count, off, N);
    fill_srcs<<<(E + 255) / 256, 256, 0, stream>>>(src, dst, off, pos, srcs, E);

    // 3) fused MLP (BM=64, 8 waves, full-width h1, one barrier)
    mlp_fused<<<Mp / 64, 512, 0, stream>>>(Ahp, Alp, B1h, B1l, b1,
                                           B2h, B2l, b2, out_nh, nhb, N);

    // 4) aggregation + eh copy in one launch
    {
        int copyB = 512;
        int aggB  = (N + 3) / 4;
        agg_copy<<<copyB + aggB, 256, 0, stream>>>(
            nhb, off, srcs, out_nh, N,
            (const float4*)eh, (float4*)out_eh, EH / 4, copyB);
    }
}

// Round 13
// 176.397 us; speedup vs baseline: 1.0126x; 1.0126x over previous
//
#include <hip/hip_runtime.h>
#include <math.h>

// ---------------------------------------------------------------------------
// GAT layer. Split-bf16 MFMA MLP (A/W hi-lo split, single-bf16 full-width h1
// in LDS, 4 waves — r11-proven) + bucketed online-softmax aggregation
// (16-lane edge groups, 2 edges/group/iter) with eh-copy folded in.
// Launch count reduced to 6 (prep zeroes count; single-launch scan).
//   n_h = relu(nh@W1+b1)@W2+b2
//   attn[e] = dot(n_h[src], n_h[dst]);  segment-softmax over dst
//   out0 = n_h + segsum(softmax * n_h[src]);  out1 = eh
// ---------------------------------------------------------------------------

#define D_IN   128
#define D_HID  256
#define D_OUT  128

typedef short bf16x8 __attribute__((ext_vector_type(8)));
typedef float f32x4  __attribute__((ext_vector_type(4)));

__device__ __forceinline__ short f2bf(float f)
{
    unsigned int u = __float_as_uint(f);
    unsigned int r = (u + 0x7fffu + ((u >> 16) & 1u)) >> 16;   // RNE
    return (short)r;
}
__device__ __forceinline__ float bf2f(short h)
{
    return __uint_as_float(((unsigned int)(unsigned short)h) << 16);
}

// ---------------------------------------------------------------------------
// pack W[K][N] fp32 into MFMA B-fragment hi/lo bf16 planes
// ---------------------------------------------------------------------------
__device__ __forceinline__ void pack_body(const float* __restrict__ W,
                                          short* __restrict__ Bh,
                                          short* __restrict__ Bl,
                                          int K, int N, int u)
{
    const int T = K >> 5;
    const int l = u & 63;
    const int t = (u >> 6) % T;
    const int c = u / (64 * T);
    const int lr = l & 15, kb = l >> 4;
    bf16x8 vh, vl;
#pragma unroll
    for (int j = 0; j < 8; ++j) {
        int k   = t * 32 + kb * 8 + j;
        int col = c * 16 + lr;
        float x = W[(size_t)k * N + col];
        short hi = f2bf(x);
        vh[j] = hi;
        vl[j] = f2bf(x - bf2f(hi));
    }
    *(bf16x8*)(Bh + (size_t)u * 8) = vh;
    *(bf16x8*)(Bl + (size_t)u * 8) = vl;
}

// ---------------------------------------------------------------------------
// prep: A hi/lo split + both weight packs + zero count (tail blocks)
// ---------------------------------------------------------------------------
__global__ __launch_bounds__(256)
void prep(const float* __restrict__ A, short* __restrict__ Ah,
          short* __restrict__ Al, long valid, long total8, int nAB,
          const float* __restrict__ W1, short* __restrict__ B1h,
          short* __restrict__ B1l,
          const float* __restrict__ W2, short* __restrict__ B2h,
          short* __restrict__ B2l,
          unsigned int* __restrict__ count, int N)
{
    int b = blockIdx.x;
    const int tid = threadIdx.x;
    if (b < nAB) {                                    // A split
        long t = (long)b * 256 + tid;
        if (t < total8) {
            long base = t * 8;
            bf16x8 vh, vl;
            if (base < valid) {
                float4 f0 = *(const float4*)(A + base);
                float4 f1 = *(const float4*)(A + base + 4);
                float fv[8] = {f0.x, f0.y, f0.z, f0.w, f1.x, f1.y, f1.z, f1.w};
#pragma unroll
                for (int j = 0; j < 8; ++j) {
                    short hi = f2bf(fv[j]);
                    vh[j] = hi;
                    vl[j] = f2bf(fv[j] - bf2f(hi));
                }
            } else {
                vh = (bf16x8)0; vl = (bf16x8)0;
            }
            *(bf16x8*)(Ah + base) = vh;
            *(bf16x8*)(Al + base) = vl;
        }
        return;
    }
    b -= nAB;
    if (b < 32) {                                     // weight packs (16+16)
        if (b < 16) pack_body(W1, B1h, B1l, D_IN, D_HID, b * 256 + tid);
        else        pack_body(W2, B2h, B2l, D_HID, D_OUT, (b - 16) * 256 + tid);
        return;
    }
    b -= 32;                                          // zero count
    int i = b * 256 + tid;
    if (i < N) count[i] = 0u;
}

// ---------------------------------------------------------------------------
// dst histogram (standalone — atomics must not share a kernel with streaming)
// ---------------------------------------------------------------------------
__global__ __launch_bounds__(256)
void hist_pos(const int* __restrict__ dst, unsigned int* __restrict__ count,
              unsigned int* __restrict__ pos, int E)
{
    int e = blockIdx.x * blockDim.x + threadIdx.x;
    if (e < E) pos[e] = atomicAdd(count + dst[e], 1u);
}

// ---------------------------------------------------------------------------
// scan_all: single-launch exclusive scan (block b redundantly sums prefix)
// ---------------------------------------------------------------------------
__global__ __launch_bounds__(256)
void scan_all(const unsigned int* __restrict__ count,
              unsigned int* __restrict__ off, int n)
{
    __shared__ unsigned int lds[256];
    const int t = threadIdx.x;
    const int b = blockIdx.x;

    unsigned int s = 0;
    for (int i = t; i < b * 256; i += 256) s += count[i];
    lds[t] = s;
    __syncthreads();
#pragma unroll
    for (int d = 128; d > 0; d >>= 1) {
        if (t < d) lds[t] += lds[t + d];
        __syncthreads();
    }
    unsigned int base = lds[0];
    __syncthreads();

    int i = b * 256 + t;
    unsigned int v = (i < n) ? count[i] : 0u;
    lds[t] = v;
    __syncthreads();
#pragma unroll
    for (int d = 1; d < 256; d <<= 1) {
        unsigned int x = lds[t];
        unsigned int add = (t >= d) ? lds[t - d] : 0u;
        __syncthreads();
        lds[t] = x + add;
        __syncthreads();
    }
    unsigned int incl = lds[t];
    if (i < n)      off[i] = base + incl - v;
    if (i == n - 1) off[n] = base + incl;
}

__global__ __launch_bounds__(256)
void fill_srcs(const int* __restrict__ src, const int* __restrict__ dst,
               const unsigned int* __restrict__ off,
               const unsigned int* __restrict__ pos,
               int* __restrict__ srcs, int E)
{
    int e = blockIdx.x * blockDim.x + threadIdx.x;
    if (e >= E) return;
    srcs[off[dst[e]] + pos[e]] = src[e];
}

// ---------------------------------------------------------------------------
// Fused MLP, BM=64, 4 waves (r11-proven). Full-width single-bf16 h1 in LDS,
// ONE barrier.
// ---------------------------------------------------------------------------
#define H2_STRIDE 264   // 256 + 8 bf16 pad

__global__ __launch_bounds__(256)
void mlp_fused(const short* __restrict__ Ah, const short* __restrict__ Al,
               const short* __restrict__ B1h, const short* __restrict__ B1l,
               const float* __restrict__ b1,
               const short* __restrict__ B2h, const short* __restrict__ B2l,
               const float* __restrict__ b2,
               float* __restrict__ out, short* __restrict__ nhb, int Nvalid)
{
    __shared__ __attribute__((aligned(16))) short H[64 * H2_STRIDE];

    const int w  = threadIdx.x >> 6;
    const int l  = threadIdx.x & 63;
    const int lr = l & 15, kb = l >> 4;
    const size_t row0 = (size_t)blockIdx.x * 64;

    // ---- GEMM1 (full width): A loaded ONCE
    f32x4 acc1[4][4] = {};
#pragma unroll
    for (int t = 0; t < 4; ++t) {
        bf16x8 ah[4], al[4], bh[4], bl[4];
#pragma unroll
        for (int m = 0; m < 4; ++m) {
            size_t aoff = (row0 + m * 16 + lr) * D_IN + t * 32 + kb * 8;
            ah[m] = *(const bf16x8*)(Ah + aoff);
            al[m] = *(const bf16x8*)(Al + aoff);
        }
#pragma unroll
        for (int n = 0; n < 4; ++n) {
            int c = w * 4 + n;
            size_t boff = (size_t)((c * 4 + t) * 64 + l) * 8;
            bh[n] = *(const bf16x8*)(B1h + boff);
            bl[n] = *(const bf16x8*)(B1l + boff);
        }
#pragma unroll
        for (int m = 0; m < 4; ++m)
#pragma unroll
            for (int n = 0; n < 4; ++n) {
                acc1[m][n] = __builtin_amdgcn_mfma_f32_16x16x32_bf16(ah[m], bh[n], acc1[m][n], 0, 0, 0);
                acc1[m][n] = __builtin_amdgcn_mfma_f32_16x16x32_bf16(al[m], bh[n], acc1[m][n], 0, 0, 0);
                acc1[m][n] = __builtin_amdgcn_mfma_f32_16x16x32_bf16(ah[m], bl[n], acc1[m][n], 0, 0, 0);
            }
    }

    // ---- bias + relu -> single bf16 -> LDS
#pragma unroll
    for (int n = 0; n < 4; ++n) {
        int col = w * 64 + n * 16 + lr;
        float bb = b1[col];
#pragma unroll
        for (int m = 0; m < 4; ++m)
#pragma unroll
            for (int i = 0; i < 4; ++i) {
                int lrow = m * 16 + kb * 4 + i;
                float v = fmaxf(acc1[m][n][i] + bb, 0.f);
                H[lrow * H2_STRIDE + col] = f2bf(v);
            }
    }
    __syncthreads();

    // ---- GEMM2: acc2 += h1 @ (W2h + W2l)
    f32x4 acc2[4][2] = {};
#pragma unroll
    for (int t2 = 0; t2 < 8; ++t2) {
        bf16x8 a[4], bh[2], bl[2];
#pragma unroll
        for (int m = 0; m < 4; ++m)
            a[m] = *(const bf16x8*)&H[(m * 16 + lr) * H2_STRIDE + t2 * 32 + kb * 8];
#pragma unroll
        for (int n = 0; n < 2; ++n) {
            int c = w * 2 + n;
            size_t boff = (size_t)((c * 8 + t2) * 64 + l) * 8;
            bh[n] = *(const bf16x8*)(B2h + boff);
            bl[n] = *(const bf16x8*)(B2l + boff);
        }
#pragma unroll
        for (int m = 0; m < 4; ++m)
#pragma unroll
            for (int n = 0; n < 2; ++n) {
                acc2[m][n] = __builtin_amdgcn_mfma_f32_16x16x32_bf16(a[m], bh[n], acc2[m][n], 0, 0, 0);
                acc2[m][n] = __builtin_amdgcn_mfma_f32_16x16x32_bf16(a[m], bl[n], acc2[m][n], 0, 0, 0);
            }
    }

    // ---- epilogue
#pragma unroll
    for (int n = 0; n < 2; ++n) {
        int col = w * 32 + n * 16 + lr;
        float bb = b2[col];
#pragma unroll
        for (int m = 0; m < 4; ++m)
#pragma unroll
            for (int i = 0; i < 4; ++i) {
                size_t row = row0 + m * 16 + kb * 4 + i;
                float v = acc2[m][n][i] + bb;
                nhb[row * D_OUT + col] = f2bf(v);
                if ((int)row < Nvalid) out[row * D_OUT + col] = v;
            }
    }
}

// ---------------------------------------------------------------------------
// agg_copy: blocks [0, copyB) stream the eh passthrough; blocks [copyB, ...)
// run node aggregation: one wave per dst node, 4 groups x 16 lanes,
// 2 edges per group per iteration (8 edges/wave-iter), online softmax.
// ---------------------------------------------------------------------------
#define NEG_HUGE -3.0e38f

__global__ __launch_bounds__(256)
void agg_copy(const short* __restrict__ nhb,
              const unsigned int* __restrict__ off,
              const int* __restrict__ srcs,
              float* __restrict__ out, int N,
              const float4* __restrict__ ehin, float4* __restrict__ ehout,
              int n4, int copyB)
{
    if ((int)blockIdx.x < copyB) {                    // eh copy
        for (int i = blockIdx.x * 256 + threadIdx.x; i < n4; i += copyB * 256)
            ehout[i] = ehin[i];
        return;
    }
    int wid  = (((int)blockIdx.x - copyB) * 256 + (int)threadIdx.x) >> 6;
    int lane = threadIdx.x & 63;
    if (wid >= N) return;
    const int g = lane >> 4;      // edge-group 0..3
    const int j = lane & 15;      // dim-lane

    const float* sp = out + (size_t)wid * D_OUT + j * 8;
    const float4 sa = *(const float4*)sp;
    const float4 sb = *(const float4*)(sp + 4);

    const unsigned int beg = off[wid];
    const unsigned int end = off[wid + 1];

    float m = NEG_HUGE, den = 0.f;
    float c0 = 0.f, c1 = 0.f, c2 = 0.f, c3 = 0.f;
    float c4 = 0.f, c5 = 0.f, c6 = 0.f, c7 = 0.f;

    for (unsigned int base = beg; base < end; base += 8) {
        unsigned int idx0 = base + g * 2;
        unsigned int idx1 = idx0 + 1;
        bool v0 = idx0 < end, v1 = idx1 < end;
        int s0 = v0 ? srcs[idx0] : 0;
        int s1 = v1 ? srcs[idx1] : 0;
        uint4 A0 = *(const uint4*)(nhb + (size_t)s0 * D_OUT + j * 8);
        uint4 A1 = *(const uint4*)(nhb + (size_t)s1 * D_OUT + j * 8);

        float a00 = __uint_as_float(A0.x << 16), a01 = __uint_as_float(A0.x & 0xffff0000u);
        float a02 = __uint_as_float(A0.y << 16), a03 = __uint_as_float(A0.y & 0xffff0000u);
        float a04 = __uint_as_float(A0.z << 16), a05 = __uint_as_float(A0.z & 0xffff0000u);
        float a06 = __uint_as_float(A0.w << 16), a07 = __uint_as_float(A0.w & 0xffff0000u);
        float a10 = __uint_as_float(A1.x << 16), a11 = __uint_as_float(A1.x & 0xffff0000u);
        float a12 = __uint_as_float(A1.y << 16), a13 = __uint_as_float(A1.y & 0xffff0000u);
        float a14 = __uint_as_float(A1.z << 16), a15 = __uint_as_float(A1.z & 0xffff0000u);
        float a16 = __uint_as_float(A1.w << 16), a17 = __uint_as_float(A1.w & 0xffff0000u);

        float p0 = a00 * sa.x + a01 * sa.y + a02 * sa.z + a03 * sa.w
                 + a04 * sb.x + a05 * sb.y + a06 * sb.z + a07 * sb.w;
        float p1 = a10 * sa.x + a11 * sa.y + a12 * sa.z + a13 * sa.w
                 + a14 * sb.x + a15 * sb.y + a16 * sb.z + a17 * sb.w;
        p0 += __shfl_xor(p0, 1);  p1 += __shfl_xor(p1, 1);
        p0 += __shfl_xor(p0, 2);  p1 += __shfl_xor(p1, 2);
        p0 += __shfl_xor(p0, 4);  p1 += __shfl_xor(p1, 4);
        p0 += __shfl_xor(p0, 8);  p1 += __shfl_xor(p1, 8);

        float p0v = v0 ? p0 : NEG_HUGE;
        float p1v = v1 ? p1 : NEG_HUGE;
        float mnew = fmaxf(m, fmaxf(p0v, p1v));
        float scale = __expf(m - mnew);
        float w0 = v0 ? __expf(p0 - mnew) : 0.f;
        float w1 = v1 ? __expf(p1 - mnew) : 0.f;
        den = fmaf(den, scale, w0 + w1);
        c0 = fmaf(c0, scale, fmaf(w0, a00, w1 * a10));
        c1 = fmaf(c1, scale, fmaf(w0, a01, w1 * a11));
        c2 = fmaf(c2, scale, fmaf(w0, a02, w1 * a12));
        c3 = fmaf(c3, scale, fmaf(w0, a03, w1 * a13));
        c4 = fmaf(c4, scale, fmaf(w0, a04, w1 * a14));
        c5 = fmaf(c5, scale, fmaf(w0, a05, w1 * a15));
        c6 = fmaf(c6, scale, fmaf(w0, a06, w1 * a16));
        c7 = fmaf(c7, scale, fmaf(w0, a07, w1 * a17));
        m = mnew;
    }

    // merge the 4 group states (flash-style)
#pragma unroll
    for (int o = 16; o < 64; o <<= 1) {
        float m2 = __shfl_xor(m, o);
        float d2 = __shfl_xor(den, o);
        float b0 = __shfl_xor(c0, o), b1 = __shfl_xor(c1, o);
        float b2v = __shfl_xor(c2, o), b3 = __shfl_xor(c3, o);
        float b4 = __shfl_xor(c4, o), b5 = __shfl_xor(c5, o);
        float b6 = __shfl_xor(c6, o), b7 = __shfl_xor(c7, o);
        float mn = fmaxf(m, m2);
        float s1 = __expf(m - mn);
        float s2 = __expf(m2 - mn);
        den = den * s1 + d2 * s2;
        c0 = c0 * s1 + b0 * s2;  c1 = c1 * s1 + b1 * s2;
        c2 = c2 * s1 + b2v * s2; c3 = c3 * s1 + b3 * s2;
        c4 = c4 * s1 + b4 * s2;  c5 = c5 * s1 + b5 * s2;
        c6 = c6 * s1 + b6 * s2;  c7 = c7 * s1 + b7 * s2;
        m = mn;
    }

    float inv = (den > 0.f) ? 1.f / den : 0.f;
    if (g == 0) {
        float4 o0, o1;
        o0.x = sa.x + c0 * inv; o0.y = sa.y + c1 * inv;
        o0.z = sa.z + c2 * inv; o0.w = sa.w + c3 * inv;
        o1.x = sb.x + c4 * inv; o1.y = sb.y + c5 * inv;
        o1.z = sb.z + c6 * inv; o1.w = sb.w + c7 * inv;
        float* op = out + (size_t)wid * D_OUT + j * 8;
        *(float4*)op = o0;
        *(float4*)(op + 4) = o1;
    }
}

// ---------------------------------------------------------------------------
extern "C" void kernel_launch(void* const* d_in, const int* in_sizes, int n_in,
                              void* d_out, int out_size, void* d_ws, size_t ws_size,
                              hipStream_t stream)
{
    const float* nh  = (const float*)d_in[0];
    const float* eh  = (const float*)d_in[1];
    const int*   ei  = (const int*)d_in[2];
    const float* W1  = (const float*)d_in[3];
    const float* b1  = (const float*)d_in[4];
    const float* W2  = (const float*)d_in[5];
    const float* b2  = (const float*)d_in[6];

    const int N  = in_sizes[0] / D_IN;        // 50000
    const int E  = in_sizes[2] / 2;           // 800000
    const int EH = in_sizes[1];               // E*16 floats
    const int Mp = (N + 63) & ~63;            // padded rows (50048)
    const int NB = (N + 255) / 256;           // scan chunks (196)

    const int* src = ei;
    const int* dst = ei + E;

    float* out_nh = (float*)d_out;
    float* out_eh = (float*)d_out + (size_t)N * D_OUT;

    // workspace (~46 MB)
    char* ws = (char*)d_ws;
    size_t o = 0;
    short* Ahp = (short*)(ws + o); o += (size_t)Mp * D_IN * 2;
    short* Alp = (short*)(ws + o); o += (size_t)Mp * D_IN * 2;
    short* nhb = (short*)(ws + o); o += (size_t)Mp * D_OUT * 2;
    short* B1h = (short*)(ws + o); o += (size_t)D_IN  * D_HID * 2;
    short* B1l = (short*)(ws + o); o += (size_t)D_IN  * D_HID * 2;
    short* B2h = (short*)(ws + o); o += (size_t)D_HID * D_OUT * 2;
    short* B2l = (short*)(ws + o); o += (size_t)D_HID * D_OUT * 2;
    int*          srcs  = (int*)(ws + o);          o += (size_t)E * 4;
    unsigned int* pos   = (unsigned int*)(ws + o); o += (size_t)E * 4;
    unsigned int* count = (unsigned int*)(ws + o); o += (size_t)N * 4;
    unsigned int* off   = (unsigned int*)(ws + o); o += (size_t)(N + 1) * 4;

    // 1) prep: A split + packs + zero count
    {
        long total8 = (long)Mp * D_IN / 8;
        int  nAB    = (int)((total8 + 255) / 256);
        prep<<<nAB + 32 + NB, 256, 0, stream>>>(
            nh, Ahp, Alp, (long)N * D_IN, total8, nAB,
            W1, B1h, B1l, W2, B2h, B2l, count, N);
    }

    // 2) histogram + single-launch scan + fill
    hist_pos<<<(E + 255) / 256, 256, 0, stream>>>(dst, count, pos, E);
    scan_all<<<NB, 256, 0, stream>>>(count, off, N);
    fill_srcs<<<(E + 255) / 256, 256, 0, stream>>>(src, dst, off, pos, srcs, E);

    // 3) fused MLP (BM=64, 4 waves, full-width h1, one barrier)
    mlp_fused<<<Mp / 64, 256, 0, stream>>>(Ahp, Alp, B1h, B1l, b1,
                                           B2h, B2l, b2, out_nh, nhb, N);

    // 4) aggregation + eh copy in one launch
    {
        int copyB = 512;
        int aggB  = (N + 3) / 4;
        agg_copy<<<copyB + aggB, 256, 0, stream>>>(
            nhb, off, srcs, out_nh, N,
            (const float4*)eh, (float4*)out_eh, EH / 4, copyB);
    }
}

// Round 15
// 160.287 us; speedup vs baseline: 1.1143x; 1.1005x over previous
//
#include <hip/hip_runtime.h>
#include <math.h>

// ---------------------------------------------------------------------------
// GAT layer — r11-exact structure (best measured: 160.8 us) + non-temporal
// eh copy (avoid L2 thrash of the gather table).
//   n_h = relu(nh@W1+b1)@W2+b2
//   attn[e] = dot(n_h[src], n_h[dst]);  segment-softmax over dst
//   out0 = n_h + segsum(softmax * n_h[src]);  out1 = eh
// ---------------------------------------------------------------------------

#define D_IN   128
#define D_HID  256
#define D_OUT  128

typedef short bf16x8 __attribute__((ext_vector_type(8)));
typedef float f32x4  __attribute__((ext_vector_type(4)));

__device__ __forceinline__ short f2bf(float f)
{
    unsigned int u = __float_as_uint(f);
    unsigned int r = (u + 0x7fffu + ((u >> 16) & 1u)) >> 16;   // RNE
    return (short)r;
}
__device__ __forceinline__ float bf2f(short h)
{
    return __uint_as_float(((unsigned int)(unsigned short)h) << 16);
}

// ---------------------------------------------------------------------------
// pack W[K][N] fp32 into MFMA B-fragment hi/lo bf16 planes
// ---------------------------------------------------------------------------
__device__ __forceinline__ void pack_body(const float* __restrict__ W,
                                          short* __restrict__ Bh,
                                          short* __restrict__ Bl,
                                          int K, int N, int u)
{
    const int T = K >> 5;
    const int l = u & 63;
    const int t = (u >> 6) % T;
    const int c = u / (64 * T);
    const int lr = l & 15, kb = l >> 4;
    bf16x8 vh, vl;
#pragma unroll
    for (int j = 0; j < 8; ++j) {
        int k   = t * 32 + kb * 8 + j;
        int col = c * 16 + lr;
        float x = W[(size_t)k * N + col];
        short hi = f2bf(x);
        vh[j] = hi;
        vl[j] = f2bf(x - bf2f(hi));
    }
    *(bf16x8*)(Bh + (size_t)u * 8) = vh;
    *(bf16x8*)(Bl + (size_t)u * 8) = vl;
}

// ---------------------------------------------------------------------------
// prep: A hi/lo split + both weight packs
// ---------------------------------------------------------------------------
__global__ __launch_bounds__(256)
void prep(const float* __restrict__ A, short* __restrict__ Ah,
          short* __restrict__ Al, long valid, long total8, int nAB,
          const float* __restrict__ W1, short* __restrict__ B1h,
          short* __restrict__ B1l,
          const float* __restrict__ W2, short* __restrict__ B2h,
          short* __restrict__ B2l)
{
    int b = blockIdx.x;
    const int tid = threadIdx.x;
    if (b < nAB) {                                    // A split
        long t = (long)b * 256 + tid;
        if (t < total8) {
            long base = t * 8;
            bf16x8 vh, vl;
            if (base < valid) {
                float4 f0 = *(const float4*)(A + base);
                float4 f1 = *(const float4*)(A + base + 4);
                float fv[8] = {f0.x, f0.y, f0.z, f0.w, f1.x, f1.y, f1.z, f1.w};
#pragma unroll
                for (int j = 0; j < 8; ++j) {
                    short hi = f2bf(fv[j]);
                    vh[j] = hi;
                    vl[j] = f2bf(fv[j] - bf2f(hi));
                }
            } else {
                vh = (bf16x8)0; vl = (bf16x8)0;
            }
            *(bf16x8*)(Ah + base) = vh;
            *(bf16x8*)(Al + base) = vl;
        }
        return;
    }
    b -= nAB;                                         // weight packs (16+16)
    if (b < 16) pack_body(W1, B1h, B1l, D_IN, D_HID, b * 256 + tid);
    else        pack_body(W2, B2h, B2l, D_HID, D_OUT, (b - 16) * 256 + tid);
}

// ---------------------------------------------------------------------------
// dst histogram (standalone — atomics must not share a kernel with streaming)
// ---------------------------------------------------------------------------
__global__ __launch_bounds__(256)
void hist_pos(const int* __restrict__ dst, unsigned int* __restrict__ count,
              unsigned int* __restrict__ pos, int E)
{
    int e = blockIdx.x * blockDim.x + threadIdx.x;
    if (e < E) pos[e] = atomicAdd(count + dst[e], 1u);
}

// ---------------------------------------------------------------------------
// bucketing: hierarchical scan (3 small kernels — measured faster than the
// single-launch redundant-prefix variant, r12/r13 regression)
// ---------------------------------------------------------------------------
__global__ __launch_bounds__(256)
void chunk_sums(const unsigned int* __restrict__ count,
                unsigned int* __restrict__ bsum, int n)
{
    __shared__ unsigned int lds[256];
    const int t = threadIdx.x;
    const int i = blockIdx.x * 256 + t;
    lds[t] = (i < n) ? count[i] : 0u;
    __syncthreads();
#pragma unroll
    for (int d = 128; d > 0; d >>= 1) {
        if (t < d) lds[t] += lds[t + d];
        __syncthreads();
    }
    if (t == 0) bsum[blockIdx.x] = lds[0];
}

__global__ __launch_bounds__(256)
void scan_sums(const unsigned int* __restrict__ bsum,
               unsigned int* __restrict__ boff, int nb)
{
    __shared__ unsigned int lds[256];
    const int t = threadIdx.x;
    unsigned int v = (t < nb) ? bsum[t] : 0u;
    lds[t] = v;
    __syncthreads();
#pragma unroll
    for (int d = 1; d < 256; d <<= 1) {
        unsigned int x = lds[t];
        unsigned int add = (t >= d) ? lds[t - d] : 0u;
        __syncthreads();
        lds[t] = x + add;
        __syncthreads();
    }
    if (t < nb) boff[t] = lds[t] - v;     // exclusive
}

__global__ __launch_bounds__(256)
void write_off(const unsigned int* __restrict__ count,
               const unsigned int* __restrict__ boff,
               unsigned int* __restrict__ off, int n)
{
    __shared__ unsigned int lds[256];
    const int t = threadIdx.x;
    const int i = blockIdx.x * 256 + t;
    unsigned int v = (i < n) ? count[i] : 0u;
    lds[t] = v;
    __syncthreads();
#pragma unroll
    for (int d = 1; d < 256; d <<= 1) {
        unsigned int x = lds[t];
        unsigned int add = (t >= d) ? lds[t - d] : 0u;
        __syncthreads();
        lds[t] = x + add;
        __syncthreads();
    }
    unsigned int incl = lds[t];
    unsigned int base = boff[blockIdx.x];
    if (i < n)  off[i] = base + incl - v;
    if (i == n - 1) off[n] = base + incl;
}

__global__ __launch_bounds__(256)
void fill_srcs(const int* __restrict__ src, const int* __restrict__ dst,
               const unsigned int* __restrict__ off,
               const unsigned int* __restrict__ pos,
               int* __restrict__ srcs, int E)
{
    int e = blockIdx.x * blockDim.x + threadIdx.x;
    if (e >= E) return;
    srcs[off[dst[e]] + pos[e]] = src[e];
}

// ---------------------------------------------------------------------------
// Fused MLP, BM=64, 4 waves. Full-width single-bf16 h1 in LDS, ONE barrier.
// ---------------------------------------------------------------------------
#define H2_STRIDE 264   // 256 + 8 bf16 pad

__global__ __launch_bounds__(256)
void mlp_fused(const short* __restrict__ Ah, const short* __restrict__ Al,
               const short* __restrict__ B1h, const short* __restrict__ B1l,
               const float* __restrict__ b1,
               const short* __restrict__ B2h, const short* __restrict__ B2l,
               const float* __restrict__ b2,
               float* __restrict__ out, short* __restrict__ nhb, int Nvalid)
{
    __shared__ __attribute__((aligned(16))) short H[64 * H2_STRIDE];

    const int w  = threadIdx.x >> 6;
    const int l  = threadIdx.x & 63;
    const int lr = l & 15, kb = l >> 4;
    const size_t row0 = (size_t)blockIdx.x * 64;

    // ---- GEMM1 (full width): A loaded ONCE
    f32x4 acc1[4][4] = {};
#pragma unroll
    for (int t = 0; t < 4; ++t) {
        bf16x8 ah[4], al[4], bh[4], bl[4];
#pragma unroll
        for (int m = 0; m < 4; ++m) {
            size_t aoff = (row0 + m * 16 + lr) * D_IN + t * 32 + kb * 8;
            ah[m] = *(const bf16x8*)(Ah + aoff);
            al[m] = *(const bf16x8*)(Al + aoff);
        }
#pragma unroll
        for (int n = 0; n < 4; ++n) {
            int c = w * 4 + n;
            size_t boff = (size_t)((c * 4 + t) * 64 + l) * 8;
            bh[n] = *(const bf16x8*)(B1h + boff);
            bl[n] = *(const bf16x8*)(B1l + boff);
        }
#pragma unroll
        for (int m = 0; m < 4; ++m)
#pragma unroll
            for (int n = 0; n < 4; ++n) {
                acc1[m][n] = __builtin_amdgcn_mfma_f32_16x16x32_bf16(ah[m], bh[n], acc1[m][n], 0, 0, 0);
                acc1[m][n] = __builtin_amdgcn_mfma_f32_16x16x32_bf16(al[m], bh[n], acc1[m][n], 0, 0, 0);
                acc1[m][n] = __builtin_amdgcn_mfma_f32_16x16x32_bf16(ah[m], bl[n], acc1[m][n], 0, 0, 0);
            }
    }

    // ---- bias + relu -> single bf16 -> LDS
#pragma unroll
    for (int n = 0; n < 4; ++n) {
        int col = w * 64 + n * 16 + lr;
        float bb = b1[col];
#pragma unroll
        for (int m = 0; m < 4; ++m)
#pragma unroll
            for (int i = 0; i < 4; ++i) {
                int lrow = m * 16 + kb * 4 + i;
                float v = fmaxf(acc1[m][n][i] + bb, 0.f);
                H[lrow * H2_STRIDE + col] = f2bf(v);
            }
    }
    __syncthreads();

    // ---- GEMM2: acc2 += h1 @ (W2h + W2l)
    f32x4 acc2[4][2] = {};
#pragma unroll
    for (int t2 = 0; t2 < 8; ++t2) {
        bf16x8 a[4], bh[2], bl[2];
#pragma unroll
        for (int m = 0; m < 4; ++m)
            a[m] = *(const bf16x8*)&H[(m * 16 + lr) * H2_STRIDE + t2 * 32 + kb * 8];
#pragma unroll
        for (int n = 0; n < 2; ++n) {
            int c = w * 2 + n;
            size_t boff = (size_t)((c * 8 + t2) * 64 + l) * 8;
            bh[n] = *(const bf16x8*)(B2h + boff);
            bl[n] = *(const bf16x8*)(B2l + boff);
        }
#pragma unroll
        for (int m = 0; m < 4; ++m)
#pragma unroll
            for (int n = 0; n < 2; ++n) {
                acc2[m][n] = __builtin_amdgcn_mfma_f32_16x16x32_bf16(a[m], bh[n], acc2[m][n], 0, 0, 0);
                acc2[m][n] = __builtin_amdgcn_mfma_f32_16x16x32_bf16(a[m], bl[n], acc2[m][n], 0, 0, 0);
            }
    }

    // ---- epilogue
#pragma unroll
    for (int n = 0; n < 2; ++n) {
        int col = w * 32 + n * 16 + lr;
        float bb = b2[col];
#pragma unroll
        for (int m = 0; m < 4; ++m)
#pragma unroll
            for (int i = 0; i < 4; ++i) {
                size_t row = row0 + m * 16 + kb * 4 + i;
                float v = acc2[m][n][i] + bb;
                nhb[row * D_OUT + col] = f2bf(v);
                if ((int)row < Nvalid) out[row * D_OUT + col] = v;
            }
    }
}

// ---------------------------------------------------------------------------
// agg_copy: blocks [0, copyB) stream the eh passthrough with NON-TEMPORAL
// loads/stores (ext_vector float4 — HIP float4 class is rejected by the
// builtin); blocks [copyB, ...) run node aggregation: one wave per dst node,
// 4 groups x 16 lanes, 2 edges per group per iteration, online softmax.
// ---------------------------------------------------------------------------
#define NEG_HUGE -3.0e38f

__global__ __launch_bounds__(256)
void agg_copy(const short* __restrict__ nhb,
              const unsigned int* __restrict__ off,
              const int* __restrict__ srcs,
              float* __restrict__ out, int N,
              const f32x4* __restrict__ ehin, f32x4* __restrict__ ehout,
              int n4, int copyB)
{
    if ((int)blockIdx.x < copyB) {                    // eh copy (non-temporal)
        for (int i = blockIdx.x * 256 + threadIdx.x; i < n4; i += copyB * 256) {
            f32x4 v = __builtin_nontemporal_load(ehin + i);
            __builtin_nontemporal_store(v, ehout + i);
        }
        return;
    }
    int wid  = (((int)blockIdx.x - copyB) * 256 + (int)threadIdx.x) >> 6;
    int lane = threadIdx.x & 63;
    if (wid >= N) return;
    const int g = lane >> 4;      // edge-group 0..3
    const int j = lane & 15;      // dim-lane

    const float* sp = out + (size_t)wid * D_OUT + j * 8;
    const float4 sa = *(const float4*)sp;
    const float4 sb = *(const float4*)(sp + 4);

    const unsigned int beg = off[wid];
    const unsigned int end = off[wid + 1];

    float m = NEG_HUGE, den = 0.f;
    float c0 = 0.f, c1 = 0.f, c2 = 0.f, c3 = 0.f;
    float c4 = 0.f, c5 = 0.f, c6 = 0.f, c7 = 0.f;

    for (unsigned int base = beg; base < end; base += 8) {
        unsigned int idx0 = base + g * 2;
        unsigned int idx1 = idx0 + 1;
        bool v0 = idx0 < end, v1 = idx1 < end;
        int s0 = v0 ? srcs[idx0] : 0;
        int s1 = v1 ? srcs[idx1] : 0;
        uint4 A0 = *(const uint4*)(nhb + (size_t)s0 * D_OUT + j * 8);
        uint4 A1 = *(const uint4*)(nhb + (size_t)s1 * D_OUT + j * 8);

        float a00 = __uint_as_float(A0.x << 16), a01 = __uint_as_float(A0.x & 0xffff0000u);
        float a02 = __uint_as_float(A0.y << 16), a03 = __uint_as_float(A0.y & 0xffff0000u);
        float a04 = __uint_as_float(A0.z << 16), a05 = __uint_as_float(A0.z & 0xffff0000u);
        float a06 = __uint_as_float(A0.w << 16), a07 = __uint_as_float(A0.w & 0xffff0000u);
        float a10 = __uint_as_float(A1.x << 16), a11 = __uint_as_float(A1.x & 0xffff0000u);
        float a12 = __uint_as_float(A1.y << 16), a13 = __uint_as_float(A1.y & 0xffff0000u);
        float a14 = __uint_as_float(A1.z << 16), a15 = __uint_as_float(A1.z & 0xffff0000u);
        float a16 = __uint_as_float(A1.w << 16), a17 = __uint_as_float(A1.w & 0xffff0000u);

        float p0 = a00 * sa.x + a01 * sa.y + a02 * sa.z + a03 * sa.w
                 + a04 * sb.x + a05 * sb.y + a06 * sb.z + a07 * sb.w;
        float p1 = a10 * sa.x + a11 * sa.y + a12 * sa.z + a13 * sa.w
                 + a14 * sb.x + a15 * sb.y + a16 * sb.z + a17 * sb.w;
        p0 += __shfl_xor(p0, 1);  p1 += __shfl_xor(p1, 1);
        p0 += __shfl_xor(p0, 2);  p1 += __shfl_xor(p1, 2);
        p0 += __shfl_xor(p0, 4);  p1 += __shfl_xor(p1, 4);
        p0 += __shfl_xor(p0, 8);  p1 += __shfl_xor(p1, 8);

        float p0v = v0 ? p0 : NEG_HUGE;
        float p1v = v1 ? p1 : NEG_HUGE;
        float mnew = fmaxf(m, fmaxf(p0v, p1v));
        float scale = __expf(m - mnew);
        float w0 = v0 ? __expf(p0 - mnew) : 0.f;
        float w1 = v1 ? __expf(p1 - mnew) : 0.f;
        den = fmaf(den, scale, w0 + w1);
        c0 = fmaf(c0, scale, fmaf(w0, a00, w1 * a10));
        c1 = fmaf(c1, scale, fmaf(w0, a01, w1 * a11));
        c2 = fmaf(c2, scale, fmaf(w0, a02, w1 * a12));
        c3 = fmaf(c3, scale, fmaf(w0, a03, w1 * a13));
        c4 = fmaf(c4, scale, fmaf(w0, a04, w1 * a14));
        c5 = fmaf(c5, scale, fmaf(w0, a05, w1 * a15));
        c6 = fmaf(c6, scale, fmaf(w0, a06, w1 * a16));
        c7 = fmaf(c7, scale, fmaf(w0, a07, w1 * a17));
        m = mnew;
    }

    // merge the 4 group states (flash-style)
#pragma unroll
    for (int o = 16; o < 64; o <<= 1) {
        float m2 = __shfl_xor(m, o);
        float d2 = __shfl_xor(den, o);
        float b0 = __shfl_xor(c0, o), b1 = __shfl_xor(c1, o);
        float b2v = __shfl_xor(c2, o), b3 = __shfl_xor(c3, o);
        float b4 = __shfl_xor(c4, o), b5 = __shfl_xor(c5, o);
        float b6 = __shfl_xor(c6, o), b7 = __shfl_xor(c7, o);
        float mn = fmaxf(m, m2);
        float s1 = __expf(m - mn);
        float s2 = __expf(m2 - mn);
        den = den * s1 + d2 * s2;
        c0 = c0 * s1 + b0 * s2;  c1 = c1 * s1 + b1 * s2;
        c2 = c2 * s1 + b2v * s2; c3 = c3 * s1 + b3 * s2;
        c4 = c4 * s1 + b4 * s2;  c5 = c5 * s1 + b5 * s2;
        c6 = c6 * s1 + b6 * s2;  c7 = c7 * s1 + b7 * s2;
        m = mn;
    }

    float inv = (den > 0.f) ? 1.f / den : 0.f;
    if (g == 0) {
        float4 o0, o1;
        o0.x = sa.x + c0 * inv; o0.y = sa.y + c1 * inv;
        o0.z = sa.z + c2 * inv; o0.w = sa.w + c3 * inv;
        o1.x = sb.x + c4 * inv; o1.y = sb.y + c5 * inv;
        o1.z = sb.z + c6 * inv; o1.w = sb.w + c7 * inv;
        float* op = out + (size_t)wid * D_OUT + j * 8;
        *(float4*)op = o0;
        *(float4*)(op + 4) = o1;
    }
}

// ---------------------------------------------------------------------------
extern "C" void kernel_launch(void* const* d_in, const int* in_sizes, int n_in,
                              void* d_out, int out_size, void* d_ws, size_t ws_size,
                              hipStream_t stream)
{
    const float* nh  = (const float*)d_in[0];
    const float* eh  = (const float*)d_in[1];
    const int*   ei  = (const int*)d_in[2];
    const float* W1  = (const float*)d_in[3];
    const float* b1  = (const float*)d_in[4];
    const float* W2  = (const float*)d_in[5];
    const float* b2  = (const float*)d_in[6];

    const int N  = in_sizes[0] / D_IN;        // 50000
    const int E  = in_sizes[2] / 2;           // 800000
    const int EH = in_sizes[1];               // E*16 floats
    const int Mp = (N + 63) & ~63;            // padded rows (50048)
    const int NB = (N + 255) / 256;           // scan chunks (196 <= 256)

    const int* src = ei;
    const int* dst = ei + E;

    float* out_nh = (float*)d_out;
    float* out_eh = (float*)d_out + (size_t)N * D_OUT;

    // workspace (~46 MB)
    char* ws = (char*)d_ws;
    size_t o = 0;
    short* Ahp = (short*)(ws + o); o += (size_t)Mp * D_IN * 2;
    short* Alp = (short*)(ws + o); o += (size_t)Mp * D_IN * 2;
    short* nhb = (short*)(ws + o); o += (size_t)Mp * D_OUT * 2;
    short* B1h = (short*)(ws + o); o += (size_t)D_IN  * D_HID * 2;
    short* B1l = (short*)(ws + o); o += (size_t)D_IN  * D_HID * 2;
    short* B2h = (short*)(ws + o); o += (size_t)D_HID * D_OUT * 2;
    short* B2l = (short*)(ws + o); o += (size_t)D_HID * D_OUT * 2;
    int*          srcs  = (int*)(ws + o);          o += (size_t)E * 4;
    unsigned int* pos   = (unsigned int*)(ws + o); o += (size_t)E * 4;
    unsigned int* count = (unsigned int*)(ws + o); o += (size_t)N * 4;
    unsigned int* off   = (unsigned int*)(ws + o); o += (size_t)(N + 1) * 4;
    unsigned int* bsum  = (unsigned int*)(ws + o); o += (size_t)NB * 4;
    unsigned int* boff  = (unsigned int*)(ws + o); o += (size_t)NB * 4;

    // 1) prep (A split + packs); memset count (r11-proven structure)
    (void)hipMemsetAsync(count, 0, (size_t)N * 4, stream);
    {
        long total8 = (long)Mp * D_IN / 8;
        int  nAB    = (int)((total8 + 255) / 256);
        prep<<<nAB + 32, 256, 0, stream>>>(
            nh, Ahp, Alp, (long)N * D_IN, total8, nAB,
            W1, B1h, B1l, W2, B2h, B2l);
    }

    // 2) histogram + 3-kernel scan + fill
    hist_pos<<<(E + 255) / 256, 256, 0, stream>>>(dst, count, pos, E);
    chunk_sums<<<NB, 256, 0, stream>>>(count, bsum, N);
    scan_sums<<<1, 256, 0, stream>>>(bsum, boff, NB);
    write_off<<<NB, 256, 0, stream>>>(count, boff, off, N);
    fill_srcs<<<(E + 255) / 256, 256, 0, stream>>>(src, dst, off, pos, srcs, E);

    // 3) fused MLP (BM=64, 4 waves, full-width h1, one barrier)
    mlp_fused<<<Mp / 64, 256, 0, stream>>>(Ahp, Alp, B1h, B1l, b1,
                                           B2h, B2l, b2, out_nh, nhb, N);

    // 4) aggregation + non-temporal eh copy in one launch
    {
        int copyB = 512;
        int aggB  = (N + 3) / 4;
        agg_copy<<<copyB + aggB, 256, 0, stream>>>(
            nhb, off, srcs, out_nh, N,
            (const f32x4*)eh, (f32x4*)out_eh, EH / 4, copyB);
    }
}